// Round 11
// baseline (166.111 us; speedup 1.0000x reference)
//
#include <hip/hip_runtime.h>
#include <stdint.h>

#define NPIX   16384
#define KC     8192
#define DD     64
#define EMS    8193          // embed row stride (K+1)
#define OUT_QUANT 0
#define OUT_DMIN  1048576
#define OUT_IND   (1048576 + 16384)

typedef _Float16 f16;
typedef _Float16 f16x8 __attribute__((ext_vector_type(8)));
typedef float    f32x4 __attribute__((ext_vector_type(4)));
typedef unsigned long long u64;

// async global->LDS, 16B/lane; dest = wave-uniform base (+lane*16 by HW)
__device__ __forceinline__ void gld_lds16(const void* g, void* l) {
    __builtin_amdgcn_global_load_lds(
        (const __attribute__((address_space(1))) uint32_t*)g,
        (__attribute__((address_space(3))) uint32_t*)l, 16, 0, 0);
}

// ---------------------------------------------------------------------------
// Prep X: split fp32 x into f16 hi/lo, store k-slot-blocked A3[16][NPIX][8].
// Slots 0..7 = Xh (d = slot*8..+7), slots 8..15 = Xl.
// ---------------------------------------------------------------------------
__global__ __launch_bounds__(256)
void vq_prep_x(const float* __restrict__ x, f16* __restrict__ A3) {
    int n = blockIdx.x * 256 + threadIdx.x;
#pragma unroll
    for (int s = 0; s < 8; ++s) {
        f16x8 hv, lv;
#pragma unroll
        for (int j = 0; j < 8; ++j) {
            float v = x[(s * 8 + j) * NPIX + n];
            f16 h = (f16)v;
            hv[j] = h;
            lv[j] = (f16)(v - (float)h);
        }
        *(f16x8*)&A3[((u64)(s)     * NPIX + n) * 8] = hv;
        *(f16x8*)&A3[((u64)(s + 8) * NPIX + n) * 8] = lv;
    }
}

// ---------------------------------------------------------------------------
// Prep E: split embed into f16 hi/lo B3[16][KC][8] + masked norms cn.
// ---------------------------------------------------------------------------
__global__ __launch_bounds__(256)
void vq_prep_e(const float* __restrict__ em, const int* __restrict__ cnt,
               f16* __restrict__ B3, float* __restrict__ cn) {
    int k = blockIdx.x * 256 + threadIdx.x;
    float s2 = 0.f;
#pragma unroll
    for (int s = 0; s < 8; ++s) {
        f16x8 hv, lv;
#pragma unroll
        for (int j = 0; j < 8; ++j) {
            float v = em[(s * 8 + j) * EMS + k];
            f16 h = (f16)v;
            hv[j] = h;
            lv[j] = (f16)(v - (float)h);
            s2 = fmaf(v, v, s2);
        }
        *(f16x8*)&B3[((u64)(s)     * KC + k) * 8] = hv;
        *(f16x8*)&B3[((u64)(s + 8) * KC + k) * 8] = lv;
    }
    cn[k] = (cnt[k] < 1) ? 1.0e30f : s2;
}

// ---------------------------------------------------------------------------
// MFMA distance GEMM + fused per-group packed argmin.
// Split product: x.e = Xh.Eh + Xl.Eh + Xh.El  -> 6 K-steps of 32 (K=192).
// Block: 128 pixels x 512 codes (4 ns-subtiles), 4 waves, wave quad 64x64.
// A-FRAGMENTS IN REGISTERS for the whole block (16 x f16x8 = 64 VGPR,
// extracted once from LDS); ONE shared 32 KB buffer: A staged -> frags
// read -> same buffer reused for B each ns. Per kt only 4 bf ds_reads ->
// MFMA-bound; 3 blocks/CU (12 waves). No per-lane global loads (R9 trap).
// ---------------------------------------------------------------------------
__global__ __launch_bounds__(256, 3)
void vq_mfma(const f16* __restrict__ A3, const f16* __restrict__ B3,
             const float* __restrict__ cn, u64* __restrict__ pk) {
    __shared__ f16 Ls[16384];   // [16 slot][128][8] -- A, then B per ns

    const int bid = blockIdx.x;
    const int nb  = bid >> 7;        // 0..15 (512-code groups)
    const int mb  = bid & 127;       // 0..127 (128-pixel tiles)
    const int m0  = mb * 128;
    const int n0  = nb * 512;
    const int t = threadIdx.x, lane = t & 63, w = t >> 6;
    const int wr = w >> 1, wc = w & 1;
    const int l15 = lane & 15, l4 = lane >> 4;

    u64 rmin[16];
#pragma unroll
    for (int i = 0; i < 16; ++i) rmin[i] = ~0ull;

    const f32x4 zero4 = {0.f, 0.f, 0.f, 0.f};

    // ---- stage A tile [16][128][8] into Ls ----
#pragma unroll
    for (int j = 0; j < 8; ++j) {
        int q = w * 8 + j;           // 0..31: slot q>>1, half q&1
        gld_lds16(A3 + ((u64)(q >> 1) * NPIX + m0 + (q & 1) * 64 + lane) * 8,
                  Ls + q * 512);
    }
    __syncthreads();                 // A resident

    // ---- extract this wave's 16 A fragments to registers (held all block) ----
    f16x8 afAll[4][4];               // [sa/4][m]
#pragma unroll
    for (int s = 0; s < 4; ++s)
#pragma unroll
        for (int m = 0; m < 4; ++m)
            afAll[s][m] = *(const f16x8*)
                &Ls[((s * 4 + l4) * 128 + wr * 64 + m * 16 + l15) * 8];
    __syncthreads();                 // all waves done reading A (lgkm drained)

    // ---- stage B for ns=0 into the same buffer ----
#pragma unroll
    for (int j = 0; j < 8; ++j) {
        int q = w * 8 + j;
        gld_lds16(B3 + ((u64)(q >> 1) * KC + n0 + (q & 1) * 64 + lane) * 8,
                  Ls + q * 512);
    }
    __syncthreads();                 // B(ns=0) resident

    static const int sidx_t[6] = {0, 1, 2, 3, 0, 1};
    static const int sb_t[6]   = {0, 4, 0, 4, 8, 12};

#pragma unroll 1
    for (int ns = 0; ns < 4; ++ns) {
        const int nsub = n0 + ns * 128;

        f32x4 acc[4][4];
#pragma unroll
        for (int m = 0; m < 4; ++m)
#pragma unroll
            for (int n = 0; n < 4; ++n) acc[m][n] = zero4;

#pragma unroll
        for (int kt = 0; kt < 6; ++kt) {
            const int sb = sb_t[kt], si = sidx_t[kt];
            f16x8 bf[4];
#pragma unroll
            for (int n = 0; n < 4; ++n)
                bf[n] = *(const f16x8*)
                    &Ls[((sb + l4) * 128 + wc * 64 + n * 16 + l15) * 8];
#pragma unroll
            for (int m = 0; m < 4; ++m)
#pragma unroll
                for (int n = 0; n < 4; ++n)
                    acc[m][n] = __builtin_amdgcn_mfma_f32_16x16x32_f16(
                        afAll[si][m], bf[n], acc[m][n], 0, 0, 0);
        }

        // ---- epilogue: dist = cn - 2*dot (+1024 bias), pack, running min ----
        const int cb = nsub + wc * 64 + l15;
        float cnv[4];
        int   col[4];
#pragma unroll
        for (int n = 0; n < 4; ++n) { col[n] = cb + n * 16; cnv[n] = cn[col[n]]; }
#pragma unroll
        for (int m = 0; m < 4; ++m)
#pragma unroll
            for (int r = 0; r < 4; ++r) {
                u64 best = rmin[m * 4 + r];
#pragma unroll
                for (int n = 0; n < 4; ++n) {
                    float dist = fmaf(-2.f, acc[m][n][r], cnv[n]) + 1024.f;
                    u64 p = ((u64)__float_as_uint(dist) << 32) | (u64)col[n];
                    best = (p < best) ? p : best;
                }
                rmin[m * 4 + r] = best;
            }

        // ---- restage B for next ns into the shared buffer ----
        if (ns < 3) {
            __syncthreads();         // all waves done reading B(ns)
#pragma unroll
            for (int j = 0; j < 8; ++j) {
                int q = w * 8 + j;
                gld_lds16(B3 + ((u64)(q >> 1) * KC + nsub + 128 + (q & 1) * 64 + lane) * 8,
                          Ls + q * 512);
            }
            __syncthreads();         // vmcnt drain + barrier
        }
    }

    // ---- 16-lane reduce, one write per (group,row) ----
    const u64 pkb = (u64)(nb * 2 + wc) * NPIX;
#pragma unroll
    for (int m = 0; m < 4; ++m)
#pragma unroll
        for (int r = 0; r < 4; ++r) {
            u64 v = rmin[m * 4 + r];
#pragma unroll
            for (int off = 1; off < 16; off <<= 1) {
                u64 o = __shfl_xor(v, off, 64);
                v = (o < v) ? o : v;
            }
            if (l15 == 0) {
                int row = m0 + wr * 64 + m * 16 + l4 * 4 + r;
                pk[pkb + row] = v;
            }
        }
}

// ---------------------------------------------------------------------------
// Finalize: global top-2 candidates from 32 group minima, exact fp32
// recompute of both distances, strict-< / lowest-index pick, write outputs.
// ---------------------------------------------------------------------------
__global__ __launch_bounds__(256)
void vq_finalize(const float* __restrict__ x, const float* __restrict__ em,
                 const float* __restrict__ cn, const u64* __restrict__ pk,
                 float* __restrict__ out) {
    int n = blockIdx.x * 256 + threadIdx.x;
    u64 b1 = ~0ull, b2 = ~0ull;
#pragma unroll 4
    for (int g = 0; g < 32; ++g) {
        u64 v = pk[(u64)g * NPIX + n];
        if (v < b1)      { b2 = b1; b1 = v; }
        else if (v < b2) { b2 = v; }
    }
    int i1 = (int)(b1 & 0xffffffffull);
    int i2 = (int)(b2 & 0xffffffffull);

    float rn = 0.f, dot1 = 0.f, dot2 = 0.f;
#pragma unroll 8
    for (int d = 0; d < DD; ++d) {
        float xv = x[d * NPIX + n];
        rn   = fmaf(xv, xv, rn);
        dot1 = fmaf(xv, em[d * EMS + i1], dot1);
        dot2 = fmaf(xv, em[d * EMS + i2], dot2);
    }
    float D1 = rn + cn[i1] - 2.f * dot1;
    float D2 = rn + cn[i2] - 2.f * dot2;
    int bi; float db;
    if (D2 < D1 || (D2 == D1 && i2 < i1)) { bi = i2; db = D2; }
    else                                  { bi = i1; db = D1; }

    out[OUT_DMIN + n] = db;
    out[OUT_IND  + n] = (float)bi;
#pragma unroll 8
    for (int d = 0; d < DD; ++d)
        out[OUT_QUANT + d * NPIX + n] = em[d * EMS + bi];
}

// ---------------------------------------------------------------------------
extern "C" void kernel_launch(void* const* d_in, const int* in_sizes, int n_in,
                              void* d_out, int out_size, void* d_ws, size_t ws_size,
                              hipStream_t stream) {
    const float* x     = (const float*)d_in[0];   // [1,64,128,128]
    const float* embed = (const float*)d_in[1];   // [64,8193]
    const int*   cnt   = (const int*)d_in[2];     // [8192]
    float* out = (float*)d_out;

    // ws layout: A3 4MB | B3 2MB | pk 4MB | cn 32KB   (10.06 MB total)
    f16*   A3 = (f16*)d_ws;
    f16*   B3 = (f16*)((char*)d_ws + (size_t)4 * 1024 * 1024);
    u64*   pk = (u64*)((char*)d_ws + (size_t)6 * 1024 * 1024);
    float* cn = (float*)((char*)d_ws + (size_t)10 * 1024 * 1024);

    vq_prep_x<<<NPIX / 256, 256, 0, stream>>>(x, A3);
    vq_prep_e<<<KC / 256, 256, 0, stream>>>(embed, cnt, B3, cn);
    vq_mfma<<<128 * 16, 256, 0, stream>>>(A3, B3, cn, pk);
    vq_finalize<<<NPIX / 256, 256, 0, stream>>>(x, embed, cn, pk, out);
}

// Round 12
// 111.382 us; speedup vs baseline: 1.4914x; 1.4914x over previous
//
#include <hip/hip_runtime.h>
#include <stdint.h>

#define NPIX   16384
#define KC     8192
#define DD     64
#define EMS    8193          // embed row stride (K+1)
#define OUT_QUANT 0
#define OUT_DMIN  1048576
#define OUT_IND   (1048576 + 16384)

typedef _Float16 f16;
typedef _Float16 f16x8 __attribute__((ext_vector_type(8)));
typedef float    f32x4 __attribute__((ext_vector_type(4)));
typedef unsigned long long u64;

// async global->LDS, 16B/lane; dest = wave-uniform base (+lane*16 by HW)
__device__ __forceinline__ void gld_lds16(const void* g, void* l) {
    __builtin_amdgcn_global_load_lds(
        (const __attribute__((address_space(1))) uint32_t*)g,
        (__attribute__((address_space(3))) uint32_t*)l, 16, 0, 0);
}

// ---------------------------------------------------------------------------
// Prep X: split fp32 x into f16 hi/lo, store k-slot-blocked A3[16][NPIX][8].
// Slots 0..7 = Xh (d = slot*8..+7), slots 8..15 = Xl.
// ---------------------------------------------------------------------------
__global__ __launch_bounds__(256)
void vq_prep_x(const float* __restrict__ x, f16* __restrict__ A3) {
    int n = blockIdx.x * 256 + threadIdx.x;
#pragma unroll
    for (int s = 0; s < 8; ++s) {
        f16x8 hv, lv;
#pragma unroll
        for (int j = 0; j < 8; ++j) {
            float v = x[(s * 8 + j) * NPIX + n];
            f16 h = (f16)v;
            hv[j] = h;
            lv[j] = (f16)(v - (float)h);
        }
        *(f16x8*)&A3[((u64)(s)     * NPIX + n) * 8] = hv;
        *(f16x8*)&A3[((u64)(s + 8) * NPIX + n) * 8] = lv;
    }
}

// ---------------------------------------------------------------------------
// Prep E: split embed into f16 hi/lo B3[16][KC][8] + masked norms cn.
// ---------------------------------------------------------------------------
__global__ __launch_bounds__(256)
void vq_prep_e(const float* __restrict__ em, const int* __restrict__ cnt,
               f16* __restrict__ B3, float* __restrict__ cn) {
    int k = blockIdx.x * 256 + threadIdx.x;
    float s2 = 0.f;
#pragma unroll
    for (int s = 0; s < 8; ++s) {
        f16x8 hv, lv;
#pragma unroll
        for (int j = 0; j < 8; ++j) {
            float v = em[(s * 8 + j) * EMS + k];
            f16 h = (f16)v;
            hv[j] = h;
            lv[j] = (f16)(v - (float)h);
            s2 = fmaf(v, v, s2);
        }
        *(f16x8*)&B3[((u64)(s)     * KC + k) * 8] = hv;
        *(f16x8*)&B3[((u64)(s + 8) * KC + k) * 8] = lv;
    }
    cn[k] = (cnt[k] < 1) ? 1.0e30f : s2;
}

// ---------------------------------------------------------------------------
// MFMA distance GEMM + fused per-group packed argmin.
// Split product: x.e = Xh.Eh + Xl.Eh + Xh.El  -> 6 K-steps of 32 (K=192).
// Block: 128 pixels x 512 codes (4 ns-subtiles), 4 waves, wave quad 64x64.
// R10 envelope (64KB LDS As+Bs, launch_bounds(256,2), 7 barriers, no
// per-lane global loads) + R11's idea WITHOUT the register-cap trap:
// the wave's 16 A-fragments are extracted to registers ONCE (64 VGPR,
// budget 256) and the kt loop reads only 4 bf frags -> 4:1 MFMA:ds_read,
// LDS pipe drops below the MFMA pipe (10.8k vs 15.8k cyc/CU-generation).
// ---------------------------------------------------------------------------
__global__ __launch_bounds__(256, 2)
void vq_mfma(const f16* __restrict__ A3, const f16* __restrict__ B3,
             const float* __restrict__ cn, u64* __restrict__ pk) {
    __shared__ f16 As[16384];   // [16 slot][128 row][8]
    __shared__ f16 Bs[16384];   // [16 slot][128 code][8]

    const int bid = blockIdx.x;
    const int nb  = bid >> 7;        // 0..15 (512-code groups)
    const int mb  = bid & 127;       // 0..127 (128-pixel tiles)
    const int m0  = mb * 128;
    const int n0  = nb * 512;
    const int t = threadIdx.x, lane = t & 63, w = t >> 6;
    const int wr = w >> 1, wc = w & 1;
    const int l15 = lane & 15, l4 = lane >> 4;

    u64 rmin[16];
#pragma unroll
    for (int i = 0; i < 16; ++i) rmin[i] = ~0ull;

    const f32x4 zero4 = {0.f, 0.f, 0.f, 0.f};

    // ---- stage A (whole block, once) + B for ns=0 ----
#pragma unroll
    for (int j = 0; j < 8; ++j) {
        int q = w * 8 + j;           // 0..31: slot q>>1, half q&1
        gld_lds16(A3 + ((u64)(q >> 1) * NPIX + m0 + (q & 1) * 64 + lane) * 8,
                  As + q * 512);
        gld_lds16(B3 + ((u64)(q >> 1) * KC + n0 + (q & 1) * 64 + lane) * 8,
                  Bs + q * 512);
    }
    __syncthreads();                 // vmcnt drain + barrier: A and B(0) live

    // ---- extract this wave's 16 A fragments to registers (whole block) ----
    f16x8 afAll[4][4];               // [sa/4][m]
#pragma unroll
    for (int s = 0; s < 4; ++s)
#pragma unroll
        for (int m = 0; m < 4; ++m)
            afAll[s][m] = *(const f16x8*)
                &As[((s * 4 + l4) * 128 + wr * 64 + m * 16 + l15) * 8];

    static const int sidx_t[6] = {0, 1, 2, 3, 0, 1};
    static const int sb_t[6]   = {0, 4, 0, 4, 8, 12};

#pragma unroll 1
    for (int ns = 0; ns < 4; ++ns) {
        const int nsub = n0 + ns * 128;

        f32x4 acc[4][4];
#pragma unroll
        for (int m = 0; m < 4; ++m)
#pragma unroll
            for (int n = 0; n < 4; ++n) acc[m][n] = zero4;

#pragma unroll
        for (int kt = 0; kt < 6; ++kt) {
            const int sb = sb_t[kt], si = sidx_t[kt];
            f16x8 bf[4];
#pragma unroll
            for (int n = 0; n < 4; ++n)
                bf[n] = *(const f16x8*)
                    &Bs[((sb + l4) * 128 + wc * 64 + n * 16 + l15) * 8];
#pragma unroll
            for (int m = 0; m < 4; ++m)
#pragma unroll
                for (int n = 0; n < 4; ++n)
                    acc[m][n] = __builtin_amdgcn_mfma_f32_16x16x32_f16(
                        afAll[si][m], bf[n], acc[m][n], 0, 0, 0);
        }

        // ---- epilogue: dist = cn - 2*dot (+1024 bias), pack, running min ----
        const int cb = nsub + wc * 64 + l15;
        float cnv[4];
        int   col[4];
#pragma unroll
        for (int n = 0; n < 4; ++n) { col[n] = cb + n * 16; cnv[n] = cn[col[n]]; }
#pragma unroll
        for (int m = 0; m < 4; ++m)
#pragma unroll
            for (int r = 0; r < 4; ++r) {
                u64 best = rmin[m * 4 + r];
#pragma unroll
                for (int n = 0; n < 4; ++n) {
                    float dist = fmaf(-2.f, acc[m][n][r], cnv[n]) + 1024.f;
                    u64 p = ((u64)__float_as_uint(dist) << 32) | (u64)col[n];
                    best = (p < best) ? p : best;
                }
                rmin[m * 4 + r] = best;
            }

        // ---- restage B for next ns ----
        if (ns < 3) {
            __syncthreads();         // all waves done reading Bs
#pragma unroll
            for (int j = 0; j < 8; ++j) {
                int q = w * 8 + j;
                gld_lds16(B3 + ((u64)(q >> 1) * KC + nsub + 128 + (q & 1) * 64 + lane) * 8,
                          Bs + q * 512);
            }
            __syncthreads();         // vmcnt drain + barrier
        }
    }

    // ---- 16-lane reduce, one write per (group,row) ----
    const u64 pkb = (u64)(nb * 2 + wc) * NPIX;
#pragma unroll
    for (int m = 0; m < 4; ++m)
#pragma unroll
        for (int r = 0; r < 4; ++r) {
            u64 v = rmin[m * 4 + r];
#pragma unroll
            for (int off = 1; off < 16; off <<= 1) {
                u64 o = __shfl_xor(v, off, 64);
                v = (o < v) ? o : v;
            }
            if (l15 == 0) {
                int row = m0 + wr * 64 + m * 16 + l4 * 4 + r;
                pk[pkb + row] = v;
            }
        }
}

// ---------------------------------------------------------------------------
// Finalize: global top-2 candidates from 32 group minima, exact fp32
// recompute of both distances, strict-< / lowest-index pick, write outputs.
// ---------------------------------------------------------------------------
__global__ __launch_bounds__(256)
void vq_finalize(const float* __restrict__ x, const float* __restrict__ em,
                 const float* __restrict__ cn, const u64* __restrict__ pk,
                 float* __restrict__ out) {
    int n = blockIdx.x * 256 + threadIdx.x;
    u64 b1 = ~0ull, b2 = ~0ull;
#pragma unroll 4
    for (int g = 0; g < 32; ++g) {
        u64 v = pk[(u64)g * NPIX + n];
        if (v < b1)      { b2 = b1; b1 = v; }
        else if (v < b2) { b2 = v; }
    }
    int i1 = (int)(b1 & 0xffffffffull);
    int i2 = (int)(b2 & 0xffffffffull);

    float rn = 0.f, dot1 = 0.f, dot2 = 0.f;
#pragma unroll 8
    for (int d = 0; d < DD; ++d) {
        float xv = x[d * NPIX + n];
        rn   = fmaf(xv, xv, rn);
        dot1 = fmaf(xv, em[d * EMS + i1], dot1);
        dot2 = fmaf(xv, em[d * EMS + i2], dot2);
    }
    float D1 = rn + cn[i1] - 2.f * dot1;
    float D2 = rn + cn[i2] - 2.f * dot2;
    int bi; float db;
    if (D2 < D1 || (D2 == D1 && i2 < i1)) { bi = i2; db = D2; }
    else                                  { bi = i1; db = D1; }

    out[OUT_DMIN + n] = db;
    out[OUT_IND  + n] = (float)bi;
#pragma unroll 8
    for (int d = 0; d < DD; ++d)
        out[OUT_QUANT + d * NPIX + n] = em[d * EMS + bi];
}

// ---------------------------------------------------------------------------
extern "C" void kernel_launch(void* const* d_in, const int* in_sizes, int n_in,
                              void* d_out, int out_size, void* d_ws, size_t ws_size,
                              hipStream_t stream) {
    const float* x     = (const float*)d_in[0];   // [1,64,128,128]
    const float* embed = (const float*)d_in[1];   // [64,8193]
    const int*   cnt   = (const int*)d_in[2];     // [8192]
    float* out = (float*)d_out;

    // ws layout: A3 4MB | B3 2MB | pk 4MB | cn 32KB   (10.06 MB total)
    f16*   A3 = (f16*)d_ws;
    f16*   B3 = (f16*)((char*)d_ws + (size_t)4 * 1024 * 1024);
    u64*   pk = (u64*)((char*)d_ws + (size_t)6 * 1024 * 1024);
    float* cn = (float*)((char*)d_ws + (size_t)10 * 1024 * 1024);

    vq_prep_x<<<NPIX / 256, 256, 0, stream>>>(x, A3);
    vq_prep_e<<<KC / 256, 256, 0, stream>>>(embed, cnt, B3, cn);
    vq_mfma<<<128 * 16, 256, 0, stream>>>(A3, B3, cn, pk);
    vq_finalize<<<NPIX / 256, 256, 0, stream>>>(x, embed, cn, pk, out);
}

// Round 13
// 106.501 us; speedup vs baseline: 1.5597x; 1.0458x over previous
//
#include <hip/hip_runtime.h>
#include <stdint.h>

#define NPIX   16384
#define KC     8192
#define DD     64
#define EMS    8193          // embed row stride (K+1)
#define OUT_QUANT 0
#define OUT_DMIN  1048576
#define OUT_IND   (1048576 + 16384)

typedef _Float16 f16;
typedef _Float16 f16x8 __attribute__((ext_vector_type(8)));
typedef float    f32x4 __attribute__((ext_vector_type(4)));
typedef unsigned long long u64;

// async global->LDS, 16B/lane; dest = wave-uniform base (+lane*16 by HW)
__device__ __forceinline__ void gld_lds16(const void* g, void* l) {
    __builtin_amdgcn_global_load_lds(
        (const __attribute__((address_space(1))) uint32_t*)g,
        (__attribute__((address_space(3))) uint32_t*)l, 16, 0, 0);
}

// ---------------------------------------------------------------------------
// Prep X: split fp32 x into f16 hi/lo, store k-slot-blocked A3[16][NPIX][8].
// Slots 0..7 = Xh (d = slot*8..+7), slots 8..15 = Xl.
// ---------------------------------------------------------------------------
__global__ __launch_bounds__(256)
void vq_prep_x(const float* __restrict__ x, f16* __restrict__ A3) {
    int n = blockIdx.x * 256 + threadIdx.x;
#pragma unroll
    for (int s = 0; s < 8; ++s) {
        f16x8 hv, lv;
#pragma unroll
        for (int j = 0; j < 8; ++j) {
            float v = x[(s * 8 + j) * NPIX + n];
            f16 h = (f16)v;
            hv[j] = h;
            lv[j] = (f16)(v - (float)h);
        }
        *(f16x8*)&A3[((u64)(s)     * NPIX + n) * 8] = hv;
        *(f16x8*)&A3[((u64)(s + 8) * NPIX + n) * 8] = lv;
    }
}

// ---------------------------------------------------------------------------
// Prep E: split embed into f16 hi/lo B3[16][KC][8] + masked norms cn.
// cn carries a +1024 bias (keeps packed distances positive; folded out in
// finalize) -- saves a per-candidate v_add in the mfma epilogue.
// ---------------------------------------------------------------------------
__global__ __launch_bounds__(256)
void vq_prep_e(const float* __restrict__ em, const int* __restrict__ cnt,
               f16* __restrict__ B3, float* __restrict__ cn) {
    int k = blockIdx.x * 256 + threadIdx.x;
    float s2 = 0.f;
#pragma unroll
    for (int s = 0; s < 8; ++s) {
        f16x8 hv, lv;
#pragma unroll
        for (int j = 0; j < 8; ++j) {
            float v = em[(s * 8 + j) * EMS + k];
            f16 h = (f16)v;
            hv[j] = h;
            lv[j] = (f16)(v - (float)h);
            s2 = fmaf(v, v, s2);
        }
        *(f16x8*)&B3[((u64)(s)     * KC + k) * 8] = hv;
        *(f16x8*)&B3[((u64)(s + 8) * KC + k) * 8] = lv;
    }
    cn[k] = (cnt[k] < 1) ? 1.0e30f : (s2 + 1024.f);
}

// ---------------------------------------------------------------------------
// MFMA distance GEMM + fused per-group packed argmin, 2-phase pipelined.
// Split product: x.e = Xh.Eh + Xl.Eh + Xh.El  -> 6 K-steps of 32 (K=192).
// Block: 128 pixels x 512 codes (4 ns-subtiles), 4 waves, wave quad 64x64.
// A-fragments extracted to registers once (64 VGPR); A's 32 KB LDS buffer
// is then REUSED as the second B buffer: B(ns+1) staging issues BEFORE the
// 6-kt compute of ns, so the ~500cy L2 drain hides under ~3700cy of MFMA.
// One barrier per ns (was 2 + exposed drain). No per-lane global loads.
// ---------------------------------------------------------------------------
__global__ __launch_bounds__(256, 2)
void vq_mfma(const f16* __restrict__ A3, const f16* __restrict__ B3,
             const float* __restrict__ cn, u64* __restrict__ pk) {
    __shared__ f16 Ls[2][16384];   // [buf][16 slot][128][8]

    const int bid = blockIdx.x;
    const int nb  = bid >> 7;        // 0..15 (512-code groups)
    const int mb  = bid & 127;       // 0..127 (128-pixel tiles)
    const int m0  = mb * 128;
    const int n0  = nb * 512;
    const int t = threadIdx.x, lane = t & 63, w = t >> 6;
    const int wr = w >> 1, wc = w & 1;
    const int l15 = lane & 15, l4 = lane >> 4;

    u64 rmin[16];
#pragma unroll
    for (int i = 0; i < 16; ++i) rmin[i] = ~0ull;

    const f32x4 zero4 = {0.f, 0.f, 0.f, 0.f};

    // ---- prologue: stage A -> Ls[1], B(ns=0) -> Ls[0] ----
#pragma unroll
    for (int j = 0; j < 8; ++j) {
        int q = w * 8 + j;           // 0..31: slot q>>1, half q&1
        gld_lds16(A3 + ((u64)(q >> 1) * NPIX + m0 + (q & 1) * 64 + lane) * 8,
                  &Ls[1][q * 512]);
        gld_lds16(B3 + ((u64)(q >> 1) * KC + n0 + (q & 1) * 64 + lane) * 8,
                  &Ls[0][q * 512]);
    }
    __syncthreads();                 // A and B(0) resident

    // ---- extract this wave's 16 A fragments to registers (whole block) ----
    f16x8 afAll[4][4];               // [sa/4][m]
#pragma unroll
    for (int s = 0; s < 4; ++s)
#pragma unroll
        for (int m = 0; m < 4; ++m)
            afAll[s][m] = *(const f16x8*)
                &Ls[1][((s * 4 + l4) * 128 + wr * 64 + m * 16 + l15) * 8];
    __syncthreads();                 // all waves done reading Ls[1]

    static const int sidx_t[6] = {0, 1, 2, 3, 0, 1};
    static const int sb_t[6]   = {0, 4, 0, 4, 8, 12};

#pragma unroll 1
    for (int ns = 0; ns < 4; ++ns) {
        const int nsub = n0 + ns * 128;
        const f16* bc = &Ls[ns & 1][0];

        // ---- issue next-ns B staging into the idle buffer (covered by
        //      this ns's compute; drained by the end-of-ns barrier) ----
        if (ns < 3) {
            f16* bo = &Ls[(ns & 1) ^ 1][0];
#pragma unroll
            for (int j = 0; j < 8; ++j) {
                int q = w * 8 + j;
                gld_lds16(B3 + ((u64)(q >> 1) * KC + nsub + 128 + (q & 1) * 64 + lane) * 8,
                          bo + q * 512);
            }
        }

        f32x4 acc[4][4];
#pragma unroll
        for (int m = 0; m < 4; ++m)
#pragma unroll
            for (int n = 0; n < 4; ++n) acc[m][n] = zero4;

#pragma unroll
        for (int kt = 0; kt < 6; ++kt) {
            const int sb = sb_t[kt], si = sidx_t[kt];
            f16x8 bf[4];
#pragma unroll
            for (int n = 0; n < 4; ++n)
                bf[n] = *(const f16x8*)
                    &bc[((sb + l4) * 128 + wc * 64 + n * 16 + l15) * 8];
#pragma unroll
            for (int m = 0; m < 4; ++m)
#pragma unroll
                for (int n = 0; n < 4; ++n)
                    acc[m][n] = __builtin_amdgcn_mfma_f32_16x16x32_f16(
                        afAll[si][m], bf[n], acc[m][n], 0, 0, 0);
        }

        // ---- epilogue: dist = cn(biased) - 2*dot, pack, running min ----
        const int cb = nsub + wc * 64 + l15;
        float cnv[4];
        int   col[4];
#pragma unroll
        for (int n = 0; n < 4; ++n) { col[n] = cb + n * 16; cnv[n] = cn[col[n]]; }
#pragma unroll
        for (int m = 0; m < 4; ++m)
#pragma unroll
            for (int r = 0; r < 4; ++r) {
                u64 best = rmin[m * 4 + r];
#pragma unroll
                for (int n = 0; n < 4; ++n) {
                    float dist = fmaf(-2.f, acc[m][n][r], cnv[n]);
                    u64 p = ((u64)__float_as_uint(dist) << 32) | (u64)col[n];
                    best = (p < best) ? p : best;
                }
                rmin[m * 4 + r] = best;
            }

        if (ns < 3) __syncthreads();   // staged B(ns+1) resident; bufs swap
    }

    // ---- 16-lane reduce, one write per (group,row) ----
    const u64 pkb = (u64)(nb * 2 + wc) * NPIX;
#pragma unroll
    for (int m = 0; m < 4; ++m)
#pragma unroll
        for (int r = 0; r < 4; ++r) {
            u64 v = rmin[m * 4 + r];
#pragma unroll
            for (int off = 1; off < 16; off <<= 1) {
                u64 o = __shfl_xor(v, off, 64);
                v = (o < v) ? o : v;
            }
            if (l15 == 0) {
                int row = m0 + wr * 64 + m * 16 + l4 * 4 + r;
                pk[pkb + row] = v;
            }
        }
}

// ---------------------------------------------------------------------------
// Finalize: global top-2 candidates from 32 group minima, exact fp32
// recompute of both distances (cn bias folded out), strict-< / lowest-index
// pick, write outputs.
// ---------------------------------------------------------------------------
__global__ __launch_bounds__(256)
void vq_finalize(const float* __restrict__ x, const float* __restrict__ em,
                 const float* __restrict__ cn, const u64* __restrict__ pk,
                 float* __restrict__ out) {
    int n = blockIdx.x * 256 + threadIdx.x;
    u64 b1 = ~0ull, b2 = ~0ull;
#pragma unroll 4
    for (int g = 0; g < 32; ++g) {
        u64 v = pk[(u64)g * NPIX + n];
        if (v < b1)      { b2 = b1; b1 = v; }
        else if (v < b2) { b2 = v; }
    }
    int i1 = (int)(b1 & 0xffffffffull);
    int i2 = (int)(b2 & 0xffffffffull);

    float rn = 0.f, dot1 = 0.f, dot2 = 0.f;
#pragma unroll 8
    for (int d = 0; d < DD; ++d) {
        float xv = x[d * NPIX + n];
        rn   = fmaf(xv, xv, rn);
        dot1 = fmaf(xv, em[d * EMS + i1], dot1);
        dot2 = fmaf(xv, em[d * EMS + i2], dot2);
    }
    float D1 = rn + (cn[i1] - 1024.f) - 2.f * dot1;
    float D2 = rn + (cn[i2] - 1024.f) - 2.f * dot2;
    int bi; float db;
    if (D2 < D1 || (D2 == D1 && i2 < i1)) { bi = i2; db = D2; }
    else                                  { bi = i1; db = D1; }

    out[OUT_DMIN + n] = db;
    out[OUT_IND  + n] = (float)bi;
#pragma unroll 8
    for (int d = 0; d < DD; ++d)
        out[OUT_QUANT + d * NPIX + n] = em[d * EMS + bi];
}

// ---------------------------------------------------------------------------
extern "C" void kernel_launch(void* const* d_in, const int* in_sizes, int n_in,
                              void* d_out, int out_size, void* d_ws, size_t ws_size,
                              hipStream_t stream) {
    const float* x     = (const float*)d_in[0];   // [1,64,128,128]
    const float* embed = (const float*)d_in[1];   // [64,8193]
    const int*   cnt   = (const int*)d_in[2];     // [8192]
    float* out = (float*)d_out;

    // ws layout: A3 4MB | B3 2MB | pk 4MB | cn 32KB   (10.06 MB total)
    f16*   A3 = (f16*)d_ws;
    f16*   B3 = (f16*)((char*)d_ws + (size_t)4 * 1024 * 1024);
    u64*   pk = (u64*)((char*)d_ws + (size_t)6 * 1024 * 1024);
    float* cn = (float*)((char*)d_ws + (size_t)10 * 1024 * 1024);

    vq_prep_x<<<NPIX / 256, 256, 0, stream>>>(x, A3);
    vq_prep_e<<<KC / 256, 256, 0, stream>>>(embed, cnt, B3, cn);
    vq_mfma<<<128 * 16, 256, 0, stream>>>(A3, B3, cn, pk);
    vq_finalize<<<NPIX / 256, 256, 0, stream>>>(x, embed, cn, pk, out);
}

// Round 14
// 98.276 us; speedup vs baseline: 1.6902x; 1.0837x over previous
//
#include <hip/hip_runtime.h>
#include <stdint.h>

#define NPIX   16384
#define KC     8192
#define DD     64
#define EMS    8193          // embed row stride (K+1)
#define OUT_QUANT 0
#define OUT_DMIN  1048576
#define OUT_IND   (1048576 + 16384)

typedef _Float16 f16;
typedef _Float16 f16x8 __attribute__((ext_vector_type(8)));
typedef float    f32x4 __attribute__((ext_vector_type(4)));
typedef unsigned long long u64;

// async global->LDS, 16B/lane; dest = wave-uniform base (+lane*16 by HW)
__device__ __forceinline__ void gld_lds16(const void* g, void* l) {
    __builtin_amdgcn_global_load_lds(
        (const __attribute__((address_space(1))) uint32_t*)g,
        (__attribute__((address_space(3))) uint32_t*)l, 16, 0, 0);
}

// ---------------------------------------------------------------------------
// Prep X: split fp32 x into f16 hi/lo, store k-slot-blocked A3[16][NPIX][8].
// Slots 0..7 = Xh (d = slot*8..+7), slots 8..15 = Xl.
// ---------------------------------------------------------------------------
__global__ __launch_bounds__(256)
void vq_prep_x(const float* __restrict__ x, f16* __restrict__ A3) {
    int n = blockIdx.x * 256 + threadIdx.x;
#pragma unroll
    for (int s = 0; s < 8; ++s) {
        f16x8 hv, lv;
#pragma unroll
        for (int j = 0; j < 8; ++j) {
            float v = x[(s * 8 + j) * NPIX + n];
            f16 h = (f16)v;
            hv[j] = h;
            lv[j] = (f16)(v - (float)h);
        }
        *(f16x8*)&A3[((u64)(s)     * NPIX + n) * 8] = hv;
        *(f16x8*)&A3[((u64)(s + 8) * NPIX + n) * 8] = lv;
    }
}

// ---------------------------------------------------------------------------
// Prep E: split embed into f16 hi/lo B3[16][KC][8] + masked norms cn.
// cn carries a +1024 bias (folded out in finalize).
// ---------------------------------------------------------------------------
__global__ __launch_bounds__(256)
void vq_prep_e(const float* __restrict__ em, const int* __restrict__ cnt,
               f16* __restrict__ B3, float* __restrict__ cn) {
    int k = blockIdx.x * 256 + threadIdx.x;
    float s2 = 0.f;
#pragma unroll
    for (int s = 0; s < 8; ++s) {
        f16x8 hv, lv;
#pragma unroll
        for (int j = 0; j < 8; ++j) {
            float v = em[(s * 8 + j) * EMS + k];
            f16 h = (f16)v;
            hv[j] = h;
            lv[j] = (f16)(v - (float)h);
            s2 = fmaf(v, v, s2);
        }
        *(f16x8*)&B3[((u64)(s)     * KC + k) * 8] = hv;
        *(f16x8*)&B3[((u64)(s + 8) * KC + k) * 8] = lv;
    }
    cn[k] = (cnt[k] < 1) ? 1.0e30f : (s2 + 1024.f);
}

// ---------------------------------------------------------------------------
// MFMA distance GEMM + fused per-block packed argmin, 2-phase pipelined.
// Split product: x.e = Xh.Eh + Xl.Eh + Xh.El  -> 6 K-steps of 32 (K=192).
// Block: 128 pixels x 512 codes, 8 ns-subtiles of 64 codes. Wave w owns
// rows w*32..+31 and covers ALL cols -> one pk group per block (16 total).
// A-fragments (8 x f16x8 = 32 VGPR) load DIRECTLY from global in the
// prologue (one-time, coalesced, L2-hot -- not R9's in-loop trap).
// B double-buffered in LDS: 2 x [16 slot][64 code][8] = 32 KB total ->
// 3 blocks/CU (12 waves, +50% TLP vs R13). launch_bounds cap 170 >> ~140.
// ---------------------------------------------------------------------------
__global__ __launch_bounds__(256, 3)
void vq_mfma(const f16* __restrict__ A3, const f16* __restrict__ B3,
             const float* __restrict__ cn, u64* __restrict__ pk) {
    __shared__ f16 Bs[2][8192];   // [buf][16 slot][64 code][8]

    const int bid = blockIdx.x;
    const int nb  = bid >> 7;        // 0..15 (512-code groups)
    const int mb  = bid & 127;       // 0..127 (128-pixel tiles)
    const int m0  = mb * 128;
    const int n0  = nb * 512;
    const int t = threadIdx.x, lane = t & 63, w = t >> 6;
    const int l15 = lane & 15, l4 = lane >> 4;
    const int wrow = m0 + w * 32;    // wave's 32 rows

    u64 rmin[8];                     // [m 2][r 4]
#pragma unroll
    for (int i = 0; i < 8; ++i) rmin[i] = ~0ull;

    const f32x4 zero4 = {0.f, 0.f, 0.f, 0.f};

    // ---- prologue: A fragments from global (held in regs all block) ----
    f16x8 afAll[4][2];               // [sa/4][m]
#pragma unroll
    for (int s = 0; s < 4; ++s)
#pragma unroll
        for (int m = 0; m < 2; ++m)
            afAll[s][m] = *(const f16x8*)
                &A3[((u64)(s * 4 + l4) * NPIX + wrow + m * 16 + l15) * 8];

    // ---- stage B(ns=0) into buf 0: 16 x 1KB instrs, 4 per wave ----
#pragma unroll
    for (int j = 0; j < 4; ++j) {
        int q = w * 4 + j;           // slot 0..15
        gld_lds16(B3 + ((u64)q * KC + n0 + lane) * 8, &Bs[0][q * 512]);
    }
    __syncthreads();                 // B(0) resident

    static const int sidx_t[6] = {0, 1, 2, 3, 0, 1};
    static const int sb_t[6]   = {0, 4, 0, 4, 8, 12};

#pragma unroll 1
    for (int ns = 0; ns < 8; ++ns) {
        const int nsub = n0 + ns * 64;
        const f16* bc = &Bs[ns & 1][0];

        // ---- issue next-ns B staging into the idle buffer ----
        if (ns < 7) {
            f16* bo = &Bs[(ns & 1) ^ 1][0];
#pragma unroll
            for (int j = 0; j < 4; ++j) {
                int q = w * 4 + j;
                gld_lds16(B3 + ((u64)q * KC + nsub + 64 + lane) * 8,
                          bo + q * 512);
            }
        }

        f32x4 acc[2][4];
#pragma unroll
        for (int m = 0; m < 2; ++m)
#pragma unroll
            for (int n = 0; n < 4; ++n) acc[m][n] = zero4;

#pragma unroll
        for (int kt = 0; kt < 6; ++kt) {
            const int sb = sb_t[kt], si = sidx_t[kt];
            f16x8 bf[4];
#pragma unroll
            for (int n = 0; n < 4; ++n)
                bf[n] = *(const f16x8*)
                    &bc[((sb + l4) * 64 + n * 16 + l15) * 8];
#pragma unroll
            for (int m = 0; m < 2; ++m)
#pragma unroll
                for (int n = 0; n < 4; ++n)
                    acc[m][n] = __builtin_amdgcn_mfma_f32_16x16x32_f16(
                        afAll[si][m], bf[n], acc[m][n], 0, 0, 0);
        }

        // ---- epilogue: dist = cn(biased) - 2*dot, pack, running min ----
        const int cb = nsub + l15;
        float cnv[4];
        int   col[4];
#pragma unroll
        for (int n = 0; n < 4; ++n) { col[n] = cb + n * 16; cnv[n] = cn[col[n]]; }
#pragma unroll
        for (int m = 0; m < 2; ++m)
#pragma unroll
            for (int r = 0; r < 4; ++r) {
                u64 best = rmin[m * 4 + r];
#pragma unroll
                for (int n = 0; n < 4; ++n) {
                    float dist = fmaf(-2.f, acc[m][n][r], cnv[n]);
                    u64 p = ((u64)__float_as_uint(dist) << 32) | (u64)col[n];
                    best = (p < best) ? p : best;
                }
                rmin[m * 4 + r] = best;
            }

        if (ns < 7) __syncthreads();   // staged B(ns+1) resident; bufs swap
    }

    // ---- 16-lane (l15) reduce, one write per row; group = nb ----
    const u64 pkb = (u64)nb * NPIX;
#pragma unroll
    for (int m = 0; m < 2; ++m)
#pragma unroll
        for (int r = 0; r < 4; ++r) {
            u64 v = rmin[m * 4 + r];
#pragma unroll
            for (int off = 1; off < 16; off <<= 1) {
                u64 o = __shfl_xor(v, off, 64);
                v = (o < v) ? o : v;
            }
            if (l15 == 0) {
                int row = wrow + m * 16 + l4 * 4 + r;
                pk[pkb + row] = v;
            }
        }
}

// ---------------------------------------------------------------------------
// Finalize: global top-2 candidates from 16 group minima, exact fp32
// recompute of both distances (cn bias folded out), strict-< / lowest-index
// pick, write outputs.
// ---------------------------------------------------------------------------
__global__ __launch_bounds__(256)
void vq_finalize(const float* __restrict__ x, const float* __restrict__ em,
                 const float* __restrict__ cn, const u64* __restrict__ pk,
                 float* __restrict__ out) {
    int n = blockIdx.x * 256 + threadIdx.x;
    u64 b1 = ~0ull, b2 = ~0ull;
#pragma unroll 4
    for (int g = 0; g < 16; ++g) {
        u64 v = pk[(u64)g * NPIX + n];
        if (v < b1)      { b2 = b1; b1 = v; }
        else if (v < b2) { b2 = v; }
    }
    int i1 = (int)(b1 & 0xffffffffull);
    int i2 = (int)(b2 & 0xffffffffull);

    float rn = 0.f, dot1 = 0.f, dot2 = 0.f;
#pragma unroll 8
    for (int d = 0; d < DD; ++d) {
        float xv = x[d * NPIX + n];
        rn   = fmaf(xv, xv, rn);
        dot1 = fmaf(xv, em[d * EMS + i1], dot1);
        dot2 = fmaf(xv, em[d * EMS + i2], dot2);
    }
    float D1 = rn + (cn[i1] - 1024.f) - 2.f * dot1;
    float D2 = rn + (cn[i2] - 1024.f) - 2.f * dot2;
    int bi; float db;
    if (D2 < D1 || (D2 == D1 && i2 < i1)) { bi = i2; db = D2; }
    else                                  { bi = i1; db = D1; }

    out[OUT_DMIN + n] = db;
    out[OUT_IND  + n] = (float)bi;
#pragma unroll 8
    for (int d = 0; d < DD; ++d)
        out[OUT_QUANT + d * NPIX + n] = em[d * EMS + bi];
}

// ---------------------------------------------------------------------------
extern "C" void kernel_launch(void* const* d_in, const int* in_sizes, int n_in,
                              void* d_out, int out_size, void* d_ws, size_t ws_size,
                              hipStream_t stream) {
    const float* x     = (const float*)d_in[0];   // [1,64,128,128]
    const float* embed = (const float*)d_in[1];   // [64,8193]
    const int*   cnt   = (const int*)d_in[2];     // [8192]
    float* out = (float*)d_out;

    // ws layout: A3 4MB | B3 2MB | pk 2MB | cn 32KB   (8.03 MB total)
    f16*   A3 = (f16*)d_ws;
    f16*   B3 = (f16*)((char*)d_ws + (size_t)4 * 1024 * 1024);
    u64*   pk = (u64*)((char*)d_ws + (size_t)6 * 1024 * 1024);
    float* cn = (float*)((char*)d_ws + (size_t)8 * 1024 * 1024);

    vq_prep_x<<<NPIX / 256, 256, 0, stream>>>(x, A3);
    vq_prep_e<<<KC / 256, 256, 0, stream>>>(embed, cnt, B3, cn);
    vq_mfma<<<128 * 16, 256, 0, stream>>>(A3, B3, cn, pk);
    vq_finalize<<<NPIX / 256, 256, 0, stream>>>(x, embed, cn, pk, out);
}

// Round 15
// 81.632 us; speedup vs baseline: 2.0349x; 1.2039x over previous
//
#include <hip/hip_runtime.h>
#include <stdint.h>

#define NPIX   16384
#define KC     8192
#define DD     64
#define EMS    8193          // embed row stride (K+1)
#define OUT_QUANT 0
#define OUT_DMIN  1048576
#define OUT_IND   (1048576 + 16384)

typedef _Float16 f16;
typedef _Float16 f16x8 __attribute__((ext_vector_type(8)));
typedef float    f32x4 __attribute__((ext_vector_type(4)));
typedef unsigned long long u64;

// async global->LDS, 16B/lane; dest = wave-uniform base (+lane*16 by HW)
__device__ __forceinline__ void gld_lds16(const void* g, void* l) {
    __builtin_amdgcn_global_load_lds(
        (const __attribute__((address_space(1))) uint32_t*)g,
        (__attribute__((address_space(3))) uint32_t*)l, 16, 0, 0);
}

// ---------------------------------------------------------------------------
// Fused prep. Blocks 0..63: split x -> f16 HI only, A3[8][NPIX][8]
// (the Xl.Eh product is dropped; error ~2e-3 is covered by the exact top-2
// recompute in vq_pick). Blocks 64..95: split embed -> f16 hi/lo
// B3[16][KC][8] + masked norms cn (biased +1024; folded out in vq_pick).
// ---------------------------------------------------------------------------
__global__ __launch_bounds__(256)
void vq_prep(const float* __restrict__ x, const float* __restrict__ em,
             const int* __restrict__ cnt,
             f16* __restrict__ A3, f16* __restrict__ B3,
             float* __restrict__ cn) {
    const int b = blockIdx.x;
    if (b < 64) {
        int n = b * 256 + threadIdx.x;
#pragma unroll
        for (int s = 0; s < 8; ++s) {
            f16x8 hv;
#pragma unroll
            for (int j = 0; j < 8; ++j)
                hv[j] = (f16)x[(s * 8 + j) * NPIX + n];
            *(f16x8*)&A3[((u64)s * NPIX + n) * 8] = hv;
        }
    } else {
        int k = (b - 64) * 256 + threadIdx.x;
        float s2 = 0.f;
#pragma unroll
        for (int s = 0; s < 8; ++s) {
            f16x8 hv, lv;
#pragma unroll
            for (int j = 0; j < 8; ++j) {
                float v = em[(s * 8 + j) * EMS + k];
                f16 h = (f16)v;
                hv[j] = h;
                lv[j] = (f16)(v - (float)h);
                s2 = fmaf(v, v, s2);
            }
            *(f16x8*)&B3[((u64)(s)     * KC + k) * 8] = hv;
            *(f16x8*)&B3[((u64)(s + 8) * KC + k) * 8] = lv;
        }
        cn[k] = (cnt[k] < 1) ? 1.0e30f : (s2 + 1024.f);
    }
}

// ---------------------------------------------------------------------------
// MFMA distance GEMM + fused per-block argmin, 2-phase pipelined.
// Product: Xh.E = Xh.Eh + Xh.El  -> 4 K-steps of 32 (K=128).
// Block: 128 pixels x 512 codes, 8 ns-subtiles of 64 codes. Wave w owns
// rows w*32..+31, all cols -> one pk group per block (16 total).
// A-fragments (4 x f16x8 = 16 VGPR) from global prologue (one-time, L2).
// B double-buffered in LDS (2 x 16 KB). Epilogue tracks (f32 dist, col)
// with cmp+2 cndmask (4 VALU/cand, was 6 with u64 pack-min); pack once
// at the final write. Ties: ascending-col order + explicit cross-lane rule.
// ---------------------------------------------------------------------------
__global__ __launch_bounds__(256, 3)
void vq_mfma(const f16* __restrict__ A3, const f16* __restrict__ B3,
             const float* __restrict__ cn, u64* __restrict__ pk) {
    __shared__ f16 Bs[2][8192];   // [buf][16 slot][64 code][8]

    const int bid = blockIdx.x;
    const int nb  = bid >> 7;        // 0..15 (512-code groups)
    const int mb  = bid & 127;       // 0..127 (128-pixel tiles)
    const int m0  = mb * 128;
    const int n0  = nb * 512;
    const int t = threadIdx.x, lane = t & 63, w = t >> 6;
    const int l15 = lane & 15, l4 = lane >> 4;
    const int wrow = m0 + w * 32;    // wave's 32 rows

    float bd[8];                     // [m 2][r 4] running min dist
    int   bc[8];                     // matching col
#pragma unroll
    for (int i = 0; i < 8; ++i) { bd[i] = 3.0e38f; bc[i] = 0x7fffffff; }

    const f32x4 zero4 = {0.f, 0.f, 0.f, 0.f};

    // ---- prologue: A fragments from global (held in regs all block) ----
    f16x8 afAll[2][2];               // [sa group][m]
#pragma unroll
    for (int s = 0; s < 2; ++s)
#pragma unroll
        for (int m = 0; m < 2; ++m)
            afAll[s][m] = *(const f16x8*)
                &A3[((u64)(s * 4 + l4) * NPIX + wrow + m * 16 + l15) * 8];

    // ---- stage B(ns=0) into buf 0: 16 x 1KB instrs, 4 per wave ----
#pragma unroll
    for (int j = 0; j < 4; ++j) {
        int q = w * 4 + j;           // slot 0..15
        gld_lds16(B3 + ((u64)q * KC + n0 + lane) * 8, &Bs[0][q * 512]);
    }
    __syncthreads();                 // B(0) resident

    static const int sidx_t[4] = {0, 1, 0, 1};
    static const int sb_t[4]   = {0, 4, 8, 12};

#pragma unroll 1
    for (int ns = 0; ns < 8; ++ns) {
        const int nsub = n0 + ns * 64;
        const f16* bc_lds = &Bs[ns & 1][0];

        // ---- issue next-ns B staging into the idle buffer ----
        if (ns < 7) {
            f16* bo = &Bs[(ns & 1) ^ 1][0];
#pragma unroll
            for (int j = 0; j < 4; ++j) {
                int q = w * 4 + j;
                gld_lds16(B3 + ((u64)q * KC + nsub + 64 + lane) * 8,
                          bo + q * 512);
            }
        }

        f32x4 acc[2][4];
#pragma unroll
        for (int m = 0; m < 2; ++m)
#pragma unroll
            for (int n = 0; n < 4; ++n) acc[m][n] = zero4;

#pragma unroll
        for (int kt = 0; kt < 4; ++kt) {
            const int sb = sb_t[kt], si = sidx_t[kt];
            f16x8 bf[4];
#pragma unroll
            for (int n = 0; n < 4; ++n)
                bf[n] = *(const f16x8*)
                    &bc_lds[((sb + l4) * 64 + n * 16 + l15) * 8];
#pragma unroll
            for (int m = 0; m < 2; ++m)
#pragma unroll
                for (int n = 0; n < 4; ++n)
                    acc[m][n] = __builtin_amdgcn_mfma_f32_16x16x32_f16(
                        afAll[si][m], bf[n], acc[m][n], 0, 0, 0);
        }

        // ---- epilogue: dist = cn(biased) - 2*dot; (f32,int) running min ----
        const int cb = nsub + l15;
        float cnv[4];
        int   col[4];
#pragma unroll
        for (int n = 0; n < 4; ++n) { col[n] = cb + n * 16; cnv[n] = cn[col[n]]; }
#pragma unroll
        for (int m = 0; m < 2; ++m)
#pragma unroll
            for (int r = 0; r < 4; ++r) {
                const int i = m * 4 + r;
#pragma unroll
                for (int n = 0; n < 4; ++n) {     // ascending col: strict <
                    float dist = fmaf(-2.f, acc[m][n][r], cnv[n]);
                    if (dist < bd[i]) { bd[i] = dist; bc[i] = col[n]; }
                }
            }

        if (ns < 7) __syncthreads();   // staged B(ns+1) resident; bufs swap
    }

    // ---- 16-lane (l15) reduce with col tie-break; pack once; write ----
    const u64 pkb = (u64)nb * NPIX;
#pragma unroll
    for (int m = 0; m < 2; ++m)
#pragma unroll
        for (int r = 0; r < 4; ++r) {
            float d = bd[m * 4 + r];
            int   c = bc[m * 4 + r];
#pragma unroll
            for (int off = 1; off < 16; off <<= 1) {
                float od = __shfl_xor(d, off, 64);
                int   oc = __shfl_xor(c, off, 64);
                if (od < d || (od == d && oc < c)) { d = od; c = oc; }
            }
            if (l15 == 0) {
                int row = wrow + m * 16 + l4 * 4 + r;
                pk[pkb + row] = ((u64)__float_as_uint(d) << 32) | (u64)c;
            }
        }
}

// ---------------------------------------------------------------------------
// Pick: global top-2 candidates from 16 group minima, exact fp32 recompute
// of both distances (cn bias folded out), strict-< / lowest-index pick,
// write dmin + ind outputs and the winning index for the gather kernel.
// ---------------------------------------------------------------------------
__global__ __launch_bounds__(256)
void vq_pick(const float* __restrict__ x, const float* __restrict__ em,
             const float* __restrict__ cn, const u64* __restrict__ pk,
             float* __restrict__ out, int* __restrict__ ib) {
    int n = blockIdx.x * 256 + threadIdx.x;
    u64 b1 = ~0ull, b2 = ~0ull;
#pragma unroll 4
    for (int g = 0; g < 16; ++g) {
        u64 v = pk[(u64)g * NPIX + n];
        if (v < b1)      { b2 = b1; b1 = v; }
        else if (v < b2) { b2 = v; }
    }
    int i1 = (int)(b1 & 0xffffffffull);
    int i2 = (int)(b2 & 0xffffffffull);

    float rn = 0.f, dot1 = 0.f, dot2 = 0.f;
#pragma unroll 8
    for (int d = 0; d < DD; ++d) {
        float xv = x[d * NPIX + n];
        rn   = fmaf(xv, xv, rn);
        dot1 = fmaf(xv, em[d * EMS + i1], dot1);
        dot2 = fmaf(xv, em[d * EMS + i2], dot2);
    }
    float D1 = rn + (cn[i1] - 1024.f) - 2.f * dot1;
    float D2 = rn + (cn[i2] - 1024.f) - 2.f * dot2;
    int bi; float db;
    if (D2 < D1 || (D2 == D1 && i2 < i1)) { bi = i2; db = D2; }
    else                                  { bi = i1; db = D1; }

    out[OUT_DMIN + n] = db;
    out[OUT_IND  + n] = (float)bi;
    ib[n] = bi;
}

// ---------------------------------------------------------------------------
// Gather: quant output. 4096 blocks (one (d, n-chunk) pair each) -> huge
// TLP for the scattered em reads; writes fully coalesced.
// ---------------------------------------------------------------------------
__global__ __launch_bounds__(256)
void vq_gather(const float* __restrict__ em, const int* __restrict__ ib,
               float* __restrict__ out) {
    int id = blockIdx.x * 256 + threadIdx.x;
    int n = id & (NPIX - 1);
    int d = id >> 14;
    out[OUT_QUANT + (u64)d * NPIX + n] = em[(u64)d * EMS + ib[n]];
}

// ---------------------------------------------------------------------------
extern "C" void kernel_launch(void* const* d_in, const int* in_sizes, int n_in,
                              void* d_out, int out_size, void* d_ws, size_t ws_size,
                              hipStream_t stream) {
    const float* x     = (const float*)d_in[0];   // [1,64,128,128]
    const float* embed = (const float*)d_in[1];   // [64,8193]
    const int*   cnt   = (const int*)d_in[2];     // [8192]
    float* out = (float*)d_out;

    // ws layout: A3 2MB | B3 2MB | pk 2MB | cn 32KB | ib 64KB  (6.1 MB)
    f16*   A3 = (f16*)d_ws;
    f16*   B3 = (f16*)((char*)d_ws + (size_t)2 * 1024 * 1024);
    u64*   pk = (u64*)((char*)d_ws + (size_t)4 * 1024 * 1024);
    float* cn = (float*)((char*)d_ws + (size_t)6 * 1024 * 1024);
    int*   ib = (int*)((char*)d_ws + (size_t)6 * 1024 * 1024 + 65536);

    vq_prep<<<96, 256, 0, stream>>>(x, embed, cnt, A3, B3, cn);
    vq_mfma<<<128 * 16, 256, 0, stream>>>(A3, B3, cn, pk);
    vq_pick<<<NPIX / 256, 256, 0, stream>>>(x, embed, cn, pk, out, ib);
    vq_gather<<<NPIX * DD / 256, 256, 0, stream>>>(embed, ib, out);
}

// Round 16
// 72.945 us; speedup vs baseline: 2.2772x; 1.1191x over previous
//
#include <hip/hip_runtime.h>
#include <stdint.h>

#define NPIX   16384
#define KC     8192
#define DD     64
#define EMS    8193          // embed row stride (K+1)
#define OUT_QUANT 0
#define OUT_DMIN  1048576
#define OUT_IND   (1048576 + 16384)

typedef _Float16 f16;
typedef _Float16 f16x8 __attribute__((ext_vector_type(8)));
typedef float    f32x4 __attribute__((ext_vector_type(4)));
typedef unsigned long long u64;

// async global->LDS, 16B/lane; dest = wave-uniform base (+lane*16 by HW)
__device__ __forceinline__ void gld_lds16(const void* g, void* l) {
    __builtin_amdgcn_global_load_lds(
        (const __attribute__((address_space(1))) uint32_t*)g,
        (__attribute__((address_space(3))) uint32_t*)l, 16, 0, 0);
}

// ---------------------------------------------------------------------------
// Fused prep, parallelized over (slot, element): 768 blocks.
// Blocks 0..511   : x -> f16 HI A3[8][NPIX][8]   (thread = one (s,n))
// Blocks 512..767 : embed -> f16 hi/lo B3[16][KC][8] (thread = one (s,k));
//                   the s==0 slice also computes masked +1024-biased norms.
// ---------------------------------------------------------------------------
__global__ __launch_bounds__(256)
void vq_prep(const float* __restrict__ x, const float* __restrict__ em,
             const int* __restrict__ cnt,
             f16* __restrict__ A3, f16* __restrict__ B3,
             float* __restrict__ cn) {
    const int b = blockIdx.x;
    if (b < 512) {
        int id = b * 256 + threadIdx.x;      // (s,n)
        int n = id & (NPIX - 1);
        int s = id >> 14;
        f16x8 hv;
#pragma unroll
        for (int j = 0; j < 8; ++j)
            hv[j] = (f16)x[(s * 8 + j) * NPIX + n];
        *(f16x8*)&A3[((u64)s * NPIX + n) * 8] = hv;
    } else {
        int id = (b - 512) * 256 + threadIdx.x;   // (s,k)
        int k = id & (KC - 1);
        int s = id >> 13;
        f16x8 hv, lv;
#pragma unroll
        for (int j = 0; j < 8; ++j) {
            float v = em[(s * 8 + j) * EMS + k];
            f16 h = (f16)v;
            hv[j] = h;
            lv[j] = (f16)(v - (float)h);
        }
        *(f16x8*)&B3[((u64)(s)     * KC + k) * 8] = hv;
        *(f16x8*)&B3[((u64)(s + 8) * KC + k) * 8] = lv;
        if (s == 0) {
            float s2 = 0.f;
#pragma unroll
            for (int d = 0; d < DD; ++d) {
                float v = em[d * EMS + k];
                s2 = fmaf(v, v, s2);
            }
            cn[k] = (cnt[k] < 1) ? 1.0e30f : (s2 + 1024.f);
        }
    }
}

// ---------------------------------------------------------------------------
// MFMA distance GEMM + fused per-block argmin, 2-phase pipelined.
// Product: Xh.E = Xh.Eh + Xh.El  -> 4 K-steps of 32 (K=128).
// Block: 128 pixels x 512 codes, 8 ns-subtiles of 64 codes. Wave w owns
// rows w*32..+31, all cols -> one pk group per block (16 total).
// A-fragments in regs from a one-time global prologue. B double-buffered
// in LDS (2 x 16 KB). bf register double-buffer across kt pipelines
// ds_read latency under the MFMA cluster. Epilogue: (f32,int) running min.
// ---------------------------------------------------------------------------
__global__ __launch_bounds__(256, 3)
void vq_mfma(const f16* __restrict__ A3, const f16* __restrict__ B3,
             const float* __restrict__ cn, u64* __restrict__ pk) {
    __shared__ f16 Bs[2][8192];   // [buf][16 slot][64 code][8]

    const int bid = blockIdx.x;
    const int nb  = bid >> 7;        // 0..15 (512-code groups)
    const int mb  = bid & 127;       // 0..127 (128-pixel tiles)
    const int m0  = mb * 128;
    const int n0  = nb * 512;
    const int t = threadIdx.x, lane = t & 63, w = t >> 6;
    const int l15 = lane & 15, l4 = lane >> 4;
    const int wrow = m0 + w * 32;    // wave's 32 rows

    float bd[8];                     // [m 2][r 4] running min dist
    int   bc[8];                     // matching col
#pragma unroll
    for (int i = 0; i < 8; ++i) { bd[i] = 3.0e38f; bc[i] = 0x7fffffff; }

    const f32x4 zero4 = {0.f, 0.f, 0.f, 0.f};

    // ---- prologue: A fragments from global (held in regs all block) ----
    f16x8 afAll[2][2];               // [sa group][m]
#pragma unroll
    for (int s = 0; s < 2; ++s)
#pragma unroll
        for (int m = 0; m < 2; ++m)
            afAll[s][m] = *(const f16x8*)
                &A3[((u64)(s * 4 + l4) * NPIX + wrow + m * 16 + l15) * 8];

    // ---- stage B(ns=0) into buf 0: 16 x 1KB instrs, 4 per wave ----
#pragma unroll
    for (int j = 0; j < 4; ++j) {
        int q = w * 4 + j;           // slot 0..15
        gld_lds16(B3 + ((u64)q * KC + n0 + lane) * 8, &Bs[0][q * 512]);
    }
    __syncthreads();                 // B(0) resident

    static const int sidx_t[4] = {0, 1, 0, 1};
    static const int sb_t[4]   = {0, 4, 8, 12};

#pragma unroll 1
    for (int ns = 0; ns < 8; ++ns) {
        const int nsub = n0 + ns * 64;
        const f16* bl = &Bs[ns & 1][0];

        // ---- issue next-ns B staging into the idle buffer ----
        if (ns < 7) {
            f16* bo = &Bs[(ns & 1) ^ 1][0];
#pragma unroll
            for (int j = 0; j < 4; ++j) {
                int q = w * 4 + j;
                gld_lds16(B3 + ((u64)q * KC + nsub + 64 + lane) * 8,
                          bo + q * 512);
            }
        }

        f32x4 acc[2][4];
#pragma unroll
        for (int m = 0; m < 2; ++m)
#pragma unroll
            for (int n = 0; n < 4; ++n) acc[m][n] = zero4;

        // bf register double-buffer: preload kt=0, prefetch kt+1 pre-MFMA
        f16x8 bfA[4], bfB[4];
#pragma unroll
        for (int n = 0; n < 4; ++n)
            bfA[n] = *(const f16x8*)&bl[((sb_t[0] + l4) * 64 + n * 16 + l15) * 8];
#pragma unroll
        for (int kt = 0; kt < 4; ++kt) {
            const int si = sidx_t[kt];
            if (kt < 3) {
                const int sbn = sb_t[kt + 1];
#pragma unroll
                for (int n = 0; n < 4; ++n)
                    bfB[n] = *(const f16x8*)
                        &bl[((sbn + l4) * 64 + n * 16 + l15) * 8];
            }
#pragma unroll
            for (int m = 0; m < 2; ++m)
#pragma unroll
                for (int n = 0; n < 4; ++n)
                    acc[m][n] = __builtin_amdgcn_mfma_f32_16x16x32_f16(
                        afAll[si][m], bfA[n], acc[m][n], 0, 0, 0);
            if (kt < 3) {
#pragma unroll
                for (int n = 0; n < 4; ++n) bfA[n] = bfB[n];
            }
        }

        // ---- epilogue: dist = cn(biased) - 2*dot; (f32,int) running min ----
        const int cb = nsub + l15;
        float cnv[4];
        int   col[4];
#pragma unroll
        for (int n = 0; n < 4; ++n) { col[n] = cb + n * 16; cnv[n] = cn[col[n]]; }
#pragma unroll
        for (int m = 0; m < 2; ++m)
#pragma unroll
            for (int r = 0; r < 4; ++r) {
                const int i = m * 4 + r;
#pragma unroll
                for (int n = 0; n < 4; ++n) {     // ascending col: strict <
                    float dist = fmaf(-2.f, acc[m][n][r], cnv[n]);
                    if (dist < bd[i]) { bd[i] = dist; bc[i] = col[n]; }
                }
            }

        if (ns < 7) __syncthreads();   // staged B(ns+1) resident; bufs swap
    }

    // ---- 16-lane (l15) reduce with col tie-break; pack once; write ----
    const u64 pkb = (u64)nb * NPIX;
#pragma unroll
    for (int m = 0; m < 2; ++m)
#pragma unroll
        for (int r = 0; r < 4; ++r) {
            float d = bd[m * 4 + r];
            int   c = bc[m * 4 + r];
#pragma unroll
            for (int off = 1; off < 16; off <<= 1) {
                float od = __shfl_xor(d, off, 64);
                int   oc = __shfl_xor(c, off, 64);
                if (od < d || (od == d && oc < c)) { d = od; c = oc; }
            }
            if (l15 == 0) {
                int row = wrow + m * 16 + l4 * 4 + r;
                pk[pkb + row] = ((u64)__float_as_uint(d) << 32) | (u64)c;
            }
        }
}

// ---------------------------------------------------------------------------
// Pick: 64-thread blocks (256 blocks -> full-chip TLP for the latency-bound
// gathers). Global top-2 from 16 group minima, exact fp32 recompute, strict
// argmin semantics, write dmin + ind + winning index for the gather.
// ---------------------------------------------------------------------------
__global__ __launch_bounds__(64)
void vq_pick(const float* __restrict__ x, const float* __restrict__ em,
             const float* __restrict__ cn, const u64* __restrict__ pk,
             float* __restrict__ out, int* __restrict__ ib) {
    int n = blockIdx.x * 64 + threadIdx.x;
    u64 b1 = ~0ull, b2 = ~0ull;
#pragma unroll 4
    for (int g = 0; g < 16; ++g) {
        u64 v = pk[(u64)g * NPIX + n];
        if (v < b1)      { b2 = b1; b1 = v; }
        else if (v < b2) { b2 = v; }
    }
    int i1 = (int)(b1 & 0xffffffffull);
    int i2 = (int)(b2 & 0xffffffffull);

    float rn = 0.f, dot1 = 0.f, dot2 = 0.f;
#pragma unroll 8
    for (int d = 0; d < DD; ++d) {
        float xv = x[d * NPIX + n];
        rn   = fmaf(xv, xv, rn);
        dot1 = fmaf(xv, em[d * EMS + i1], dot1);
        dot2 = fmaf(xv, em[d * EMS + i2], dot2);
    }
    float D1 = rn + (cn[i1] - 1024.f) - 2.f * dot1;
    float D2 = rn + (cn[i2] - 1024.f) - 2.f * dot2;
    int bi; float db;
    if (D2 < D1 || (D2 == D1 && i2 < i1)) { bi = i2; db = D2; }
    else                                  { bi = i1; db = D1; }

    out[OUT_DMIN + n] = db;
    out[OUT_IND  + n] = (float)bi;
    ib[n] = bi;
}

// ---------------------------------------------------------------------------
// Gather: quant output. 4096 blocks -> huge TLP for scattered em reads;
// writes fully coalesced.
// ---------------------------------------------------------------------------
__global__ __launch_bounds__(256)
void vq_gather(const float* __restrict__ em, const int* __restrict__ ib,
               float* __restrict__ out) {
    int id = blockIdx.x * 256 + threadIdx.x;
    int n = id & (NPIX - 1);
    int d = id >> 14;
    out[OUT_QUANT + (u64)d * NPIX + n] = em[(u64)d * EMS + ib[n]];
}

// ---------------------------------------------------------------------------
extern "C" void kernel_launch(void* const* d_in, const int* in_sizes, int n_in,
                              void* d_out, int out_size, void* d_ws, size_t ws_size,
                              hipStream_t stream) {
    const float* x     = (const float*)d_in[0];   // [1,64,128,128]
    const float* embed = (const float*)d_in[1];   // [64,8193]
    const int*   cnt   = (const int*)d_in[2];     // [8192]
    float* out = (float*)d_out;

    // ws layout: A3 2MB | B3 2MB | pk 2MB | cn 32KB | ib 64KB  (6.1 MB)
    f16*   A3 = (f16*)d_ws;
    f16*   B3 = (f16*)((char*)d_ws + (size_t)2 * 1024 * 1024);
    u64*   pk = (u64*)((char*)d_ws + (size_t)4 * 1024 * 1024);
    float* cn = (float*)((char*)d_ws + (size_t)6 * 1024 * 1024);
    int*   ib = (int*)((char*)d_ws + (size_t)6 * 1024 * 1024 + 65536);

    vq_prep<<<768, 256, 0, stream>>>(x, embed, cnt, A3, B3, cn);
    vq_mfma<<<128 * 16, 256, 0, stream>>>(A3, B3, cn, pk);
    vq_pick<<<NPIX / 64, 64, 0, stream>>>(x, embed, cn, pk, out, ib);
    vq_gather<<<NPIX * DD / 256, 256, 0, stream>>>(embed, ib, out);
}